// Round 5
// baseline (656.518 us; speedup 1.0000x reference)
//
#include <hip/hip_runtime.h>
#include <stdint.h>

typedef unsigned int u32;
typedef short v8s __attribute__((ext_vector_type(8)));
typedef float v4f __attribute__((ext_vector_type(4)));

#define B_ 256
#define NF_ 1000000

__device__ inline u32 f2bf1(float a) {
    u32 x = __float_as_uint(a);
    return (x + 0x7fffu + ((x >> 16) & 1u)) >> 16;
}
__device__ inline float bfval(float a) { return __uint_as_float(f2bf1(a) << 16); }
__device__ inline u32 packbf(float lo, float hi) { return f2bf1(lo) | (f2bf1(hi) << 16); }
__device__ inline v8s as_v8s(uint4 x) { union { uint4 a; v8s b; } u; u.a = x; return u.b; }
__device__ inline v4f mfma16(v8s a, v8s b, v4f c) {
    return __builtin_amdgcn_mfma_f32_16x16x32_bf16(a, b, c, 0, 0, 0);
}

// truncation-split of 8 consecutive fp32 -> bf16 hi frag + bf16 lo frag.
// hi+lo == x exactly (sub of truncated part is exact); dropped bits ~2^-17|x|.
__device__ inline void split8(const float* p, v8s& hi, v8s& lo) {
    u32 h[4], l[4];
    #pragma unroll
    for (int i = 0; i < 4; ++i) {
        float2 f = *(const float2*)(p + 2*i);
        u32 xa = __float_as_uint(f.x), xb = __float_as_uint(f.y);
        h[i] = __builtin_amdgcn_perm(xb, xa, 0x07060302u);   // {hi16(b),hi16(a)}
        float la = f.x - __uint_as_float(xa & 0xffff0000u);
        float lb = f.y - __uint_as_float(xb & 0xffff0000u);
        l[i] = __builtin_amdgcn_perm(__float_as_uint(lb), __float_as_uint(la), 0x07060302u);
    }
    hi = as_v8s(make_uint4(h[0], h[1], h[2], h[3]));
    lo = as_v8s(make_uint4(l[0], l[1], l[2], l[3]));
}

// d_out scratch layout (dword offsets)
#define OFF_W1T_H 0
#define OFF_W1T_L 4096
#define OFF_W2T_H 8192
#define OFF_W2T_L 16384
#define OFF_DIFF_H 24576
#define OFF_DIFF_L 28672
#define OFF_WCOMP 32768
#define OFF_BCOMP 33344
#define OFF_VC    33408
#define OFF_PART  131072

// ---------------------------------------------------------------------------
// w_prep (unchanged from round 4 — verified)
// ---------------------------------------------------------------------------
__global__ __launch_bounds__(256) void w_prep(
    const float* __restrict__ x,   const float* __restrict__ w1c,
    const float* __restrict__ b1c, const float* __restrict__ w2c,
    const float* __restrict__ b2c, const float* __restrict__ w1l,
    const float* __restrict__ w2l, const float* __restrict__ diff,
    u32* __restrict__ scr)
{
    int idx = blockIdx.x * 256 + threadIdx.x;
    float* scf = (float*)scr;
    if (idx < 4096) {
        int j = idx >> 5, c = idx & 31;
        float v0 = w1l[j*64 + 2*c], v1 = w1l[j*64 + 2*c + 1];
        scr[OFF_W1T_H + idx] = packbf(v0, v1);
        scr[OFF_W1T_L + idx] = packbf(v0 - bfval(v0), v1 - bfval(v1));
    } else if (idx < 12288) {
        int r = idx - 4096, j = r >> 6, c = r & 63;
        float v0 = w2l[j*128 + 2*c], v1 = w2l[j*128 + 2*c + 1];
        scr[OFF_W2T_H + r] = packbf(v0, v1);
        scr[OFF_W2T_L + r] = packbf(v0 - bfval(v0), v1 - bfval(v1));
    } else if (idx < 16384) {
        int r = idx - 12288, a = r >> 6, c = r & 63;
        float v0 = diff[a*128 + 2*c], v1 = diff[a*128 + 2*c + 1];
        scr[OFF_DIFF_H + r] = packbf(v0, v1);
        scr[OFF_DIFF_L + r] = packbf(v0 - bfval(v0), v1 - bfval(v1));
    } else if (idx < 16960) {
        int r = idx - 16384, j = r >> 6, o = r & 63;
        float s = 0.0f;
        for (int k1 = 0; k1 < 5; ++k1) {
            int k2 = j - k1;
            if (k2 < 0 || k2 > 4) continue;
            for (int i = 0; i < 32; ++i)
                s += w1c[i*5 + k1] * w2c[o*160 + i*5 + k2];
        }
        scf[OFF_WCOMP + r] = s;
    } else if (idx < 17024) {
        int o = idx - 16960;
        float s = b2c[o];
        for (int i = 0; i < 32; ++i) {
            float b1 = b1c[i];
            for (int k2 = 0; k2 < 5; ++k2) s += w2c[o*160 + i*5 + k2] * b1;
        }
        scf[OFF_BCOMP + o] = s;
    } else if (idx >= 17408 && idx < 82944) {
        int r = idx - 17408;
        int b = r >> 8, q = (r >> 6) & 3, o = r & 63;
        float x0 = x[b*2000], x1 = x[b*2000 + 1];
        float xa = x[b*2000 + 1998], xb = x[b*2000 + 1999];
        float s = 0.0f;
        for (int i = 0; i < 32; ++i) {
            float b1 = b1c[i];
            if (q == 0) {
                float hvm2 = b1 + w1c[i*5 + 4]*x0;
                float hvm1 = b1 + w1c[i*5 + 3]*x0 + w1c[i*5 + 4]*x1;
                s += w2c[o*160 + i*5 + 0]*hvm2 + w2c[o*160 + i*5 + 1]*hvm1;
            } else if (q == 1) {
                float hvm1 = b1 + w1c[i*5 + 3]*x0 + w1c[i*5 + 4]*x1;
                s += w2c[o*160 + i*5 + 0]*hvm1;
            } else if (q == 2) {
                float hv0 = b1 + w1c[i*5 + 0]*xa + w1c[i*5 + 1]*xb;
                s += w2c[o*160 + i*5 + 4]*hv0;
            } else {
                float hv0 = b1 + w1c[i*5 + 0]*xa + w1c[i*5 + 1]*xb;
                float hv1 = b1 + w1c[i*5 + 0]*xb;
                s += w2c[o*160 + i*5 + 3]*hv0 + w2c[o*160 + i*5 + 4]*hv1;
            }
        }
        scf[OFF_VC + r] = s;
    }
}

// ---------------------------------------------------------------------------
// k_front v5: exact fp32 composite conv -> lin1/lin2 in two 64-col passes.
// Intermediates fp32 in ONE [128][66] LDS buffer (34.3 KB total -> 3 blk/CU);
// hi/lo bf16 frags built at read time via truncation-split (exact sum).
// Final e RNE-packed via ds_write_b16 into [128][65] u32 overlay.
// ---------------------------------------------------------------------------
__global__ __launch_bounds__(256, 3) void k_front(
    const float* __restrict__ x,  const float* __restrict__ b1l,
    const float* __restrict__ b2l,
    const float* __restrict__ Wc, const float* __restrict__ Bc,
    const float* __restrict__ Vc,
    const uint4* __restrict__ w1h, const uint4* __restrict__ w1lo,
    const uint4* __restrict__ w2h, const uint4* __restrict__ w2lo,
    u32* __restrict__ e)
{
    __shared__ float smf[8584];          // Abuf [128][66] | xs @8448 [136]
    float* Abuf = smf;
    float* xsf  = smf + 8448;
    u32*  est   = (u32*)smf;             // final overlay: [128][65] packed bf16
    uint16_t* esth = (uint16_t*)smf;     // halfword view, row stride 130

    const int b  = blockIdx.x >> 4;
    const int l0 = (blockIdx.x & 15) << 7;
    const int t  = threadIdx.x;
    const int lane = t & 63;
    const int w    = t >> 6;
    const int n16  = lane & 15;
    const int q    = lane >> 4;

    for (int j = t; j < 136; j += 256) {
        int g = l0 - 4 + j;
        xsf[j] = (g >= 0 && g < 2000) ? x[b*2000 + g] : 0.0f;
    }
    __syncthreads();

    // composite conv (exact fp32) -> Abuf[pos][o] fp32
    {
        const int p = t & 127;
        const int ohalf = t >> 7;                    // wave-uniform
        const int gl = l0 + p;
        float xr[9];
        #pragma unroll
        for (int j = 0; j < 9; ++j) xr[j] = xsf[p + j];
        float yv[32];
        for (int oi = 0; oi < 32; ++oi) {
            int o = ohalf*32 + oi;                   // uniform -> s_load weights
            float y = Bc[o];
            #pragma unroll
            for (int j = 0; j < 9; ++j) y += xr[j] * Wc[j*64 + o];
            if (gl <= 1)                      y -= Vc[(b*4 + gl)*64 + o];
            else if (gl >= 1998 && gl < 2000) y -= Vc[(b*4 + gl - 1996)*64 + o];
            yv[oi] = y;
        }
        #pragma unroll
        for (int ci = 0; ci < 16; ++ci)
            *(float2*)&Abuf[p*66 + ohalf*32 + 2*ci] = make_float2(yv[2*ci], yv[2*ci+1]);
    }
    __syncthreads();

    // cache A1 frags (hi/lo) in registers for both passes
    v8s a1h[2][2], a1l[2][2];
    #pragma unroll
    for (int mt = 0; mt < 2; ++mt)
        #pragma unroll
        for (int kc = 0; kc < 2; ++kc) {
            int r = (w*2 + mt)*16 + n16;
            split8(&Abuf[r*66 + kc*32 + q*8], a1h[mt][kc], a1l[mt][kc]);
        }
    __syncthreads();   // Abuf free for A2-half overlay

    v4f acc2[2][8];
    #pragma unroll
    for (int nt = 0; nt < 8; ++nt) {
        float bias = b2l[nt*16 + n16];
        acc2[0][nt] = (v4f){bias, bias, bias, bias};
        acc2[1][nt] = (v4f){bias, bias, bias, bias};
    }

    #pragma unroll
    for (int ph = 0; ph < 2; ++ph) {
        // lin1 pass: out cols j = ph*64 + nt*16 + n16, nt 0..3 -> Abuf fp32
        #pragma unroll
        for (int nt = 0; nt < 4; ++nt) {
            int j = ph*64 + nt*16 + n16;
            float bias = b1l[j];
            v4f a0 = (v4f){bias, bias, bias, bias};
            v4f a1v = a0;
            #pragma unroll
            for (int kc = 0; kc < 2; ++kc) {
                v8s bh = as_v8s(w1h [j*8 + kc*4 + q]);
                v8s bl = as_v8s(w1lo[j*8 + kc*4 + q]);
                a0  = mfma16(a1h[0][kc], bh, a0);
                a0  = mfma16(a1l[0][kc], bh, a0);
                a0  = mfma16(a1h[0][kc], bl, a0);
                a1v = mfma16(a1h[1][kc], bh, a1v);
                a1v = mfma16(a1l[1][kc], bh, a1v);
                a1v = mfma16(a1h[1][kc], bl, a1v);
            }
            #pragma unroll
            for (int rg = 0; rg < 4; ++rg) {
                int rr0 = (w*2 + 0)*16 + q*4 + rg;
                int rr1 = (w*2 + 1)*16 + q*4 + rg;
                Abuf[rr0*66 + nt*16 + n16] = fmaxf(a0[rg], 0.0f);
                Abuf[rr1*66 + nt*16 + n16] = fmaxf(a1v[rg], 0.0f);
            }
        }
        __syncthreads();

        // lin2 partial: k = ph*64 + kcl*32 + q*8
        v8s a2h[2][2], a2l[2][2];
        #pragma unroll
        for (int mt = 0; mt < 2; ++mt)
            #pragma unroll
            for (int kcl = 0; kcl < 2; ++kcl) {
                int r = (w*2 + mt)*16 + n16;
                split8(&Abuf[r*66 + kcl*32 + q*8], a2h[mt][kcl], a2l[mt][kcl]);
            }
        #pragma unroll
        for (int nt = 0; nt < 8; ++nt) {
            int j2 = nt*16 + n16;
            #pragma unroll
            for (int kcl = 0; kcl < 2; ++kcl) {
                v8s bh = as_v8s(w2h [j2*16 + ph*8 + kcl*4 + q]);
                v8s bl = as_v8s(w2lo[j2*16 + ph*8 + kcl*4 + q]);
                acc2[0][nt] = mfma16(a2h[0][kcl], bh, acc2[0][nt]);
                acc2[0][nt] = mfma16(a2l[0][kcl], bh, acc2[0][nt]);
                acc2[0][nt] = mfma16(a2h[0][kcl], bl, acc2[0][nt]);
                acc2[1][nt] = mfma16(a2h[1][kcl], bh, acc2[1][nt]);
                acc2[1][nt] = mfma16(a2l[1][kcl], bh, acc2[1][nt]);
                acc2[1][nt] = mfma16(a2h[1][kcl], bl, acc2[1][nt]);
            }
        }
        __syncthreads();   // A2-half reads done -> next pass / est overlay
    }

    // epilogue: relu + RNE bf16, per-element b16 store (no pairing shuffle)
    #pragma unroll
    for (int mt = 0; mt < 2; ++mt)
        #pragma unroll
        for (int nt = 0; nt < 8; ++nt)
            #pragma unroll
            for (int rg = 0; rg < 4; ++rg) {
                float v = fmaxf(acc2[mt][nt][rg], 0.0f);
                int rr = (w*2 + mt)*16 + q*4 + rg;
                esth[rr*130 + nt*16 + n16] = (uint16_t)f2bf1(v);
            }
    __syncthreads();

    // coalesced e store
    {
        int r = t >> 1, hh = (t & 1) * 32;
        if (l0 + r < 2000) {
            const u32* src = est + r*65 + hh;
            u32* dst = e + ((size_t)(b*2000 + l0 + r))*64 + hh;
            #pragma unroll
            for (int c = 0; c < 32; c += 4)
                *(uint4*)(dst + c) = make_uint4(src[c], src[c+1], src[c+2], src[c+3]);
        }
    }
}

// ---------------------------------------------------------------------------
// k_lse (unchanged from round 4 — verified)
// ---------------------------------------------------------------------------
__global__ __launch_bounds__(256, 2) void k_lse(
    const u32* __restrict__ e, const uint4* __restrict__ dh,
    const uint4* __restrict__ dl, const float* __restrict__ baseline,
    const int* __restrict__ regions, float* __restrict__ partials)
{
    __shared__ float sred[4][64][2];
    const int b     = blockIdx.x >> 4;
    const int chunk = blockIdx.x & 15;
    const int l0    = chunk << 7;
    const int t     = threadIdx.x;
    const int lane  = t & 63;
    const int w     = t >> 6;
    const int n16   = lane & 15;
    const int q     = lane >> 4;
    const int rrow  = regions[b];
    const int r0    = w * 32;

    v8s af[2][4];
    #pragma unroll
    for (int mt = 0; mt < 2; ++mt) {
        int rl = l0 + r0 + mt*16 + n16;
        int rc = rl < 2000 ? rl : 1999;
        const u32* er = e + ((size_t)(b*2000 + rc))*64;
        #pragma unroll
        for (int kc = 0; kc < 4; ++kc)
            af[mt][kc] = as_v8s(*(const uint4*)(er + kc*16 + q*4));
    }

    float blv[2][4];
    bool  vl[2][4];
    #pragma unroll
    for (int mt = 0; mt < 2; ++mt)
        #pragma unroll
        for (int rg = 0; rg < 4; ++rg) {
            int rl = l0 + r0 + mt*16 + q*4 + rg;
            vl[mt][rg] = rl < 2000;
            blv[mt][rg] = baseline[rrow*2000 + (rl < 2000 ? rl : 1999)];
        }

    #pragma unroll
    for (int nt = 0; nt < 4; ++nt) {
        v4f acc0 = (v4f){0.f,0.f,0.f,0.f}, acc1 = (v4f){0.f,0.f,0.f,0.f};
        #pragma unroll
        for (int kc = 0; kc < 4; ++kc) {
            v8s bh = as_v8s(dh[(nt*16 + n16)*16 + kc*4 + q]);
            v8s bl = as_v8s(dl[(nt*16 + n16)*16 + kc*4 + q]);
            acc0 = mfma16(af[0][kc], bh, acc0);
            acc1 = mfma16(af[1][kc], bh, acc1);
            acc0 = mfma16(af[0][kc], bl, acc0);
            acc1 = mfma16(af[1][kc], bl, acc1);
        }
        float m = -3.0e38f, s = 0.0f;
        #pragma unroll
        for (int rg = 0; rg < 4; ++rg) {
            float u = acc0[rg] + blv[0][rg];
            if (vl[0][rg]) {
                float mn = fmaxf(m, u);
                s = s * __expf(m - mn) + __expf(u - mn);
                m = mn;
            }
        }
        #pragma unroll
        for (int rg = 0; rg < 4; ++rg) {
            float u = acc1[rg] + blv[1][rg];
            if (vl[1][rg]) {
                float mn = fmaxf(m, u);
                s = s * __expf(m - mn) + __expf(u - mn);
                m = mn;
            }
        }
        #pragma unroll
        for (int off = 16; off < 64; off <<= 1) {
            float m2 = __shfl_xor(m, off, 64);
            float s2 = __shfl_xor(s, off, 64);
            float mn = fmaxf(m, m2);
            s = s * __expf(m - mn) + s2 * __expf(m2 - mn);
            m = mn;
        }
        if (q == 0) {
            sred[w][nt*16 + n16][0] = m;
            sred[w][nt*16 + n16][1] = s;
        }
    }
    __syncthreads();
    if (t < 64) {
        float m = sred[0][t][0], s = sred[0][t][1];
        #pragma unroll
        for (int ww = 1; ww < 4; ++ww) {
            float m2 = sred[ww][t][0], s2 = sred[ww][t][1];
            float mn = fmaxf(m, m2);
            s = s * __expf(m - mn) + s2 * __expf(m2 - mn);
            m = mn;
        }
        partials[((b*16 + chunk)*64 + t)*2 + 0] = m;
        partials[((b*16 + chunk)*64 + t)*2 + 1] = s;
    }
}

__global__ __launch_bounds__(64) void k_red(
    const float* __restrict__ partials, float* __restrict__ lse)
{
    int b = blockIdx.x, a = threadIdx.x;
    float m = -3.0e38f, s = 0.0f;
    for (int c = 0; c < 16; ++c) {
        float pm = partials[((b*16 + c)*64 + a)*2 + 0];
        float ps = partials[((b*16 + c)*64 + a)*2 + 1];
        float mn = fmaxf(m, pm);
        s = s * __expf(m - mn) + ps * __expf(pm - mn);
        m = mn;
    }
    lse[b*64 + a] = m + __logf(s);
}

// ---------------------------------------------------------------------------
// k_gather v5: 4 fragments per thread, batched index loads + interleaved
// e-row loads (4 independent chains/thread; all waves co-resident).
// ---------------------------------------------------------------------------
#define GF 4
__global__ __launch_bounds__(256) void k_gather(
    const u32* __restrict__ e, const float* __restrict__ diff,
    const float* __restrict__ baseline, const int* __restrict__ regions,
    const int* __restrict__ labels, const int* __restrict__ cellix,
    const int* __restrict__ regionix, const int* __restrict__ binix,
    const float* __restrict__ lse, float* __restrict__ out)
{
    const int base = blockIdx.x * (256*GF) + threadIdx.x;
    int f[GF], bb[GF], ll[GF], aa[GF];
    bool val[GF];
    #pragma unroll
    for (int i = 0; i < GF; ++i) {
        f[i] = base + i*256;
        val[i] = f[i] < NF_;
        int fc = val[i] ? f[i] : 0;
        bb[i] = regionix[fc];
        ll[i] = binix[fc];
        aa[i] = cellix[fc];
    }
    #pragma unroll
    for (int i = 0; i < GF; ++i) aa[i] = labels[aa[i]];

    const uint4* er[GF];
    const float* dr[GF];
    float bl[GF], ls[GF], u0[GF], u1[GF];
    #pragma unroll
    for (int i = 0; i < GF; ++i) {
        er[i] = (const uint4*)(e + ((size_t)(bb[i]*2000 + ll[i]))*64);
        dr[i] = diff + aa[i]*128;
        bl[i] = baseline[regions[bb[i]]*2000 + ll[i]];
        ls[i] = lse[bb[i]*64 + aa[i]];
        u0[i] = 0.0f; u1[i] = 0.0f;
    }

    #pragma unroll
    for (int qq = 0; qq < 16; ++qq) {
        uint4 pp[GF];
        #pragma unroll
        for (int i = 0; i < GF; ++i) pp[i] = er[i][qq];     // GF independent loads
        #pragma unroll
        for (int i = 0; i < GF; ++i) {
            const float4* d4 = (const float4*)(dr[i] + qq*8);
            float4 d0 = d4[0], d1 = d4[1];
            u0[i] += __uint_as_float(pp[i].x << 16)         * d0.x;
            u1[i] += __uint_as_float(pp[i].x & 0xffff0000u) * d0.y;
            u0[i] += __uint_as_float(pp[i].y << 16)         * d0.z;
            u1[i] += __uint_as_float(pp[i].y & 0xffff0000u) * d0.w;
            u0[i] += __uint_as_float(pp[i].z << 16)         * d1.x;
            u1[i] += __uint_as_float(pp[i].z & 0xffff0000u) * d1.y;
            u0[i] += __uint_as_float(pp[i].w << 16)         * d1.z;
            u1[i] += __uint_as_float(pp[i].w & 0xffff0000u) * d1.w;
        }
    }
    #pragma unroll
    for (int i = 0; i < GF; ++i)
        if (val[i])
            out[f[i]] = (u0[i] + u1[i]) + bl[i] - ls[i] + 5.545177444479562f;
}

extern "C" void kernel_launch(void* const* d_in, const int* in_sizes, int n_in,
                              void* d_out, int out_size, void* d_ws, size_t ws_size,
                              hipStream_t stream)
{
    const float* bincounts = (const float*)d_in[0];
    const float* conv1_w   = (const float*)d_in[1];
    const float* conv1_b   = (const float*)d_in[2];
    const float* conv2_w   = (const float*)d_in[3];
    const float* conv2_b   = (const float*)d_in[4];
    const float* lin1_w    = (const float*)d_in[5];
    const float* lin1_b    = (const float*)d_in[6];
    const float* lin2_w    = (const float*)d_in[7];
    const float* lin2_b    = (const float*)d_in[8];
    const float* baseline  = (const float*)d_in[9];
    const float* diff      = (const float*)d_in[10];
    const int*   regions   = (const int*)d_in[11];
    const int*   labels    = (const int*)d_in[12];
    const int*   cellix    = (const int*)d_in[13];
    const int*   regionix  = (const int*)d_in[14];
    const int*   binix     = (const int*)d_in[15];
    float* out = (float*)d_out;
    u32*   scr = (u32*)d_out;    // d_out doubles as scratch until k_gather

    const size_t e_words = (size_t)B_ * 2000 * 64;      // packed bf16 pairs
    const size_t need = e_words*4 + (size_t)B_*64*4;
    if (ws_size < need) return;
    u32*   e   = (u32*)d_ws;
    float* lse = (float*)(e + e_words);

    const float* scf = (const float*)scr;
    float* partials = (float*)(scr + OFF_PART);

    w_prep <<<dim3(324), dim3(256), 0, stream>>>(bincounts, conv1_w, conv1_b, conv2_w,
                                                 conv2_b, lin1_w, lin2_w, diff, scr);
    k_front<<<dim3(B_*16), dim3(256), 0, stream>>>(bincounts, lin1_b, lin2_b,
                                                   scf + OFF_WCOMP, scf + OFF_BCOMP,
                                                   scf + OFF_VC,
                                                   (const uint4*)(scr + OFF_W1T_H),
                                                   (const uint4*)(scr + OFF_W1T_L),
                                                   (const uint4*)(scr + OFF_W2T_H),
                                                   (const uint4*)(scr + OFF_W2T_L), e);
    k_lse  <<<dim3(B_*16), dim3(256), 0, stream>>>(e, (const uint4*)(scr + OFF_DIFF_H),
                                                   (const uint4*)(scr + OFF_DIFF_L),
                                                   baseline, regions, partials);
    k_red  <<<dim3(B_), dim3(64), 0, stream>>>(partials, lse);
    k_gather<<<dim3((NF_ + 256*GF - 1) / (256*GF)), dim3(256), 0, stream>>>(
        e, diff, baseline, regions, labels, cellix, regionix, binix, lse, out);
}

// Round 6
// 498.817 us; speedup vs baseline: 1.3162x; 1.3162x over previous
//
#include <hip/hip_runtime.h>
#include <stdint.h>

typedef unsigned int u32;
typedef short v8s __attribute__((ext_vector_type(8)));
typedef float v4f __attribute__((ext_vector_type(4)));

#define B_ 256
#define NF_ 1000000

__device__ inline u32 f2bf1(float a) {
    u32 x = __float_as_uint(a);
    return (x + 0x7fffu + ((x >> 16) & 1u)) >> 16;
}
__device__ inline float bfval(float a) { return __uint_as_float(f2bf1(a) << 16); }
__device__ inline u32 packbf(float lo, float hi) { return f2bf1(lo) | (f2bf1(hi) << 16); }
__device__ inline v8s as_v8s(uint4 x) { union { uint4 a; v8s b; } u; u.a = x; return u.b; }
__device__ inline v4f mfma16(v8s a, v8s b, v4f c) {
    return __builtin_amdgcn_mfma_f32_16x16x32_bf16(a, b, c, 0, 0, 0);
}

// truncation-split of 8 consecutive fp32 -> bf16 hi + lo frags (hi+lo exact)
__device__ inline void split8(const float* p, v8s& hi, v8s& lo) {
    u32 h[4], l[4];
    #pragma unroll
    for (int i = 0; i < 4; ++i) {
        float2 f = *(const float2*)(p + 2*i);
        u32 xa = __float_as_uint(f.x), xb = __float_as_uint(f.y);
        h[i] = __builtin_amdgcn_perm(xb, xa, 0x07060302u);
        float la = f.x - __uint_as_float(xa & 0xffff0000u);
        float lb = f.y - __uint_as_float(xb & 0xffff0000u);
        l[i] = __builtin_amdgcn_perm(__float_as_uint(lb), __float_as_uint(la), 0x07060302u);
    }
    hi = as_v8s(make_uint4(h[0], h[1], h[2], h[3]));
    lo = as_v8s(make_uint4(l[0], l[1], l[2], l[3]));
}

// d_out scratch layout (dword offsets)
#define OFF_W1T_H 0
#define OFF_W1T_L 4096
#define OFF_W2T_H 8192
#define OFF_W2T_L 16384
#define OFF_DIFF_H 24576
#define OFF_DIFF_L 28672
#define OFF_WCOMP 32768
#define OFF_BCOMP 33344
#define OFF_VC    33408
#define OFF_PART  131072

// ---------------------------------------------------------------------------
// w_prep (verified rounds 4-5)
// ---------------------------------------------------------------------------
__global__ __launch_bounds__(256) void w_prep(
    const float* __restrict__ x,   const float* __restrict__ w1c,
    const float* __restrict__ b1c, const float* __restrict__ w2c,
    const float* __restrict__ b2c, const float* __restrict__ w1l,
    const float* __restrict__ w2l, const float* __restrict__ diff,
    u32* __restrict__ scr)
{
    int idx = blockIdx.x * 256 + threadIdx.x;
    float* scf = (float*)scr;
    if (idx < 4096) {
        int j = idx >> 5, c = idx & 31;
        float v0 = w1l[j*64 + 2*c], v1 = w1l[j*64 + 2*c + 1];
        scr[OFF_W1T_H + idx] = packbf(v0, v1);
        scr[OFF_W1T_L + idx] = packbf(v0 - bfval(v0), v1 - bfval(v1));
    } else if (idx < 12288) {
        int r = idx - 4096, j = r >> 6, c = r & 63;
        float v0 = w2l[j*128 + 2*c], v1 = w2l[j*128 + 2*c + 1];
        scr[OFF_W2T_H + r] = packbf(v0, v1);
        scr[OFF_W2T_L + r] = packbf(v0 - bfval(v0), v1 - bfval(v1));
    } else if (idx < 16384) {
        int r = idx - 12288, a = r >> 6, c = r & 63;
        float v0 = diff[a*128 + 2*c], v1 = diff[a*128 + 2*c + 1];
        scr[OFF_DIFF_H + r] = packbf(v0, v1);
        scr[OFF_DIFF_L + r] = packbf(v0 - bfval(v0), v1 - bfval(v1));
    } else if (idx < 16960) {
        int r = idx - 16384, j = r >> 6, o = r & 63;
        float s = 0.0f;
        for (int k1 = 0; k1 < 5; ++k1) {
            int k2 = j - k1;
            if (k2 < 0 || k2 > 4) continue;
            for (int i = 0; i < 32; ++i)
                s += w1c[i*5 + k1] * w2c[o*160 + i*5 + k2];
        }
        scf[OFF_WCOMP + r] = s;
    } else if (idx < 17024) {
        int o = idx - 16960;
        float s = b2c[o];
        for (int i = 0; i < 32; ++i) {
            float b1 = b1c[i];
            for (int k2 = 0; k2 < 5; ++k2) s += w2c[o*160 + i*5 + k2] * b1;
        }
        scf[OFF_BCOMP + o] = s;
    } else if (idx >= 17408 && idx < 82944) {
        int r = idx - 17408;
        int b = r >> 8, q = (r >> 6) & 3, o = r & 63;
        float x0 = x[b*2000], x1 = x[b*2000 + 1];
        float xa = x[b*2000 + 1998], xb = x[b*2000 + 1999];
        float s = 0.0f;
        for (int i = 0; i < 32; ++i) {
            float b1 = b1c[i];
            if (q == 0) {
                float hvm2 = b1 + w1c[i*5 + 4]*x0;
                float hvm1 = b1 + w1c[i*5 + 3]*x0 + w1c[i*5 + 4]*x1;
                s += w2c[o*160 + i*5 + 0]*hvm2 + w2c[o*160 + i*5 + 1]*hvm1;
            } else if (q == 1) {
                float hvm1 = b1 + w1c[i*5 + 3]*x0 + w1c[i*5 + 4]*x1;
                s += w2c[o*160 + i*5 + 0]*hvm1;
            } else if (q == 2) {
                float hv0 = b1 + w1c[i*5 + 0]*xa + w1c[i*5 + 1]*xb;
                s += w2c[o*160 + i*5 + 4]*hv0;
            } else {
                float hv0 = b1 + w1c[i*5 + 0]*xa + w1c[i*5 + 1]*xb;
                float hv1 = b1 + w1c[i*5 + 0]*xb;
                s += w2c[o*160 + i*5 + 3]*hv0 + w2c[o*160 + i*5 + 4]*hv1;
            }
        }
        scf[OFF_VC + r] = s;
    }
}

// ---------------------------------------------------------------------------
// k_front v6: composite conv (fp32) -> lin1/lin2 split-bf16 MFMA -> e bf16
// global store -> FUSED lse U-GEMM (est-frags x diff hi/lo) + online (m,s)
// -> partials. LDS 36.4 KB -> 4 blocks/CU.
// ---------------------------------------------------------------------------
__global__ __launch_bounds__(256, 4) void k_front(
    const float* __restrict__ x,  const float* __restrict__ b1l,
    const float* __restrict__ b2l,
    const float* __restrict__ Wc, const float* __restrict__ Bc,
    const float* __restrict__ Vc,
    const uint4* __restrict__ w1h, const uint4* __restrict__ w1lo,
    const uint4* __restrict__ w2h, const uint4* __restrict__ w2lo,
    const uint4* __restrict__ dh,  const uint4* __restrict__ dl,
    const float* __restrict__ baseline, const int* __restrict__ regions,
    u32* __restrict__ e, float* __restrict__ partials)
{
    __shared__ float smf[9096];          // Abuf/est [128][66] | xs@8448 | sred@8584
    float* Abuf = smf;
    float* xsf  = smf + 8448;
    float* sred = smf + 8584;            // [4][64][2]
    u32*  estd  = (u32*)smf;             // packed bf16, row stride 66 dw
    uint16_t* esth = (uint16_t*)smf;     // halfword view, row stride 132

    const int b  = blockIdx.x >> 4;
    const int chunk = blockIdx.x & 15;
    const int l0 = chunk << 7;
    const int t  = threadIdx.x;
    const int lane = t & 63;
    const int w    = t >> 6;
    const int n16  = lane & 15;
    const int q    = lane >> 4;
    const int rrow = regions[b];

    for (int j = t; j < 136; j += 256) {
        int g = l0 - 4 + j;
        xsf[j] = (g >= 0 && g < 2000) ? x[b*2000 + g] : 0.0f;
    }
    __syncthreads();

    // composite conv (exact fp32) -> Abuf[pos][o]
    {
        const int p = t & 127;
        const int ohalf = t >> 7;
        const int gl = l0 + p;
        float xr[9];
        #pragma unroll
        for (int j = 0; j < 9; ++j) xr[j] = xsf[p + j];
        float yv[32];
        for (int oi = 0; oi < 32; ++oi) {
            int o = ohalf*32 + oi;
            float y = Bc[o];
            #pragma unroll
            for (int j = 0; j < 9; ++j) y += xr[j] * Wc[j*64 + o];
            if (gl <= 1)                      y -= Vc[(b*4 + gl)*64 + o];
            else if (gl >= 1998 && gl < 2000) y -= Vc[(b*4 + gl - 1996)*64 + o];
            yv[oi] = y;
        }
        #pragma unroll
        for (int ci = 0; ci < 16; ++ci)
            *(float2*)&Abuf[p*66 + ohalf*32 + 2*ci] = make_float2(yv[2*ci], yv[2*ci+1]);
    }
    __syncthreads();

    // cache A1 frags (hi/lo) for both passes
    v8s a1h[2][2], a1l[2][2];
    #pragma unroll
    for (int mt = 0; mt < 2; ++mt)
        #pragma unroll
        for (int kc = 0; kc < 2; ++kc) {
            int r = (w*2 + mt)*16 + n16;
            split8(&Abuf[r*66 + kc*32 + q*8], a1h[mt][kc], a1l[mt][kc]);
        }
    __syncthreads();

    v4f acc2[2][8];
    #pragma unroll
    for (int nt = 0; nt < 8; ++nt) {
        float bias = b2l[nt*16 + n16];
        acc2[0][nt] = (v4f){bias, bias, bias, bias};
        acc2[1][nt] = (v4f){bias, bias, bias, bias};
    }

    #pragma unroll
    for (int ph = 0; ph < 2; ++ph) {
        #pragma unroll
        for (int nt = 0; nt < 4; ++nt) {
            int j = ph*64 + nt*16 + n16;
            float bias = b1l[j];
            v4f a0 = (v4f){bias, bias, bias, bias};
            v4f a1v = a0;
            #pragma unroll
            for (int kc = 0; kc < 2; ++kc) {
                v8s bh = as_v8s(w1h [j*8 + kc*4 + q]);
                v8s bl = as_v8s(w1lo[j*8 + kc*4 + q]);
                a0  = mfma16(a1h[0][kc], bh, a0);
                a0  = mfma16(a1l[0][kc], bh, a0);
                a0  = mfma16(a1h[0][kc], bl, a0);
                a1v = mfma16(a1h[1][kc], bh, a1v);
                a1v = mfma16(a1l[1][kc], bh, a1v);
                a1v = mfma16(a1h[1][kc], bl, a1v);
            }
            #pragma unroll
            for (int rg = 0; rg < 4; ++rg) {
                int rr0 = (w*2 + 0)*16 + q*4 + rg;
                int rr1 = (w*2 + 1)*16 + q*4 + rg;
                Abuf[rr0*66 + nt*16 + n16] = fmaxf(a0[rg], 0.0f);
                Abuf[rr1*66 + nt*16 + n16] = fmaxf(a1v[rg], 0.0f);
            }
        }
        __syncthreads();

        v8s a2h[2][2], a2l[2][2];
        #pragma unroll
        for (int mt = 0; mt < 2; ++mt)
            #pragma unroll
            for (int kcl = 0; kcl < 2; ++kcl) {
                int r = (w*2 + mt)*16 + n16;
                split8(&Abuf[r*66 + kcl*32 + q*8], a2h[mt][kcl], a2l[mt][kcl]);
            }
        #pragma unroll
        for (int nt = 0; nt < 8; ++nt) {
            int j2 = nt*16 + n16;
            #pragma unroll
            for (int kcl = 0; kcl < 2; ++kcl) {
                v8s bh = as_v8s(w2h [j2*16 + ph*8 + kcl*4 + q]);
                v8s bl = as_v8s(w2lo[j2*16 + ph*8 + kcl*4 + q]);
                acc2[0][nt] = mfma16(a2h[0][kcl], bh, acc2[0][nt]);
                acc2[0][nt] = mfma16(a2l[0][kcl], bh, acc2[0][nt]);
                acc2[0][nt] = mfma16(a2h[0][kcl], bl, acc2[0][nt]);
                acc2[1][nt] = mfma16(a2h[1][kcl], bh, acc2[1][nt]);
                acc2[1][nt] = mfma16(a2l[1][kcl], bh, acc2[1][nt]);
                acc2[1][nt] = mfma16(a2h[1][kcl], bl, acc2[1][nt]);
            }
        }
        __syncthreads();
    }

    // epilogue: relu + RNE bf16 -> est (stride 66 dw / 132 hw)
    #pragma unroll
    for (int mt = 0; mt < 2; ++mt)
        #pragma unroll
        for (int nt = 0; nt < 8; ++nt)
            #pragma unroll
            for (int rg = 0; rg < 4; ++rg) {
                float v = fmaxf(acc2[mt][nt][rg], 0.0f);
                int rr = (w*2 + mt)*16 + q*4 + rg;
                esth[rr*132 + nt*16 + n16] = (uint16_t)f2bf1(v);
            }
    __syncthreads();

    // coalesced e store (reads est)
    {
        int r = t >> 1, hh = (t & 1) * 32;
        if (l0 + r < 2000) {
            const u32* src = estd + r*66 + hh;
            u32* dst = e + ((size_t)(b*2000 + l0 + r))*64 + hh;
            #pragma unroll
            for (int c = 0; c < 32; c += 4)
                *(uint4*)(dst + c) = make_uint4(src[c], src[c+1], src[c+2], src[c+3]);
        }
    }

    // ---- fused lse: U = est @ diffT + base, online (m,s), partials ----
    const int r0 = w * 32;
    v8s af[2][4];
    #pragma unroll
    for (int mt = 0; mt < 2; ++mt)
        #pragma unroll
        for (int kc = 0; kc < 4; ++kc) {
            int base = (r0 + mt*16 + n16)*66 + kc*16 + q*4;
            uint2 p0 = *(const uint2*)(estd + base);
            uint2 p1 = *(const uint2*)(estd + base + 2);
            af[mt][kc] = as_v8s(make_uint4(p0.x, p0.y, p1.x, p1.y));
        }

    float blv[2][4];
    bool  vl[2][4];
    #pragma unroll
    for (int mt = 0; mt < 2; ++mt)
        #pragma unroll
        for (int rg = 0; rg < 4; ++rg) {
            int rl = l0 + r0 + mt*16 + q*4 + rg;
            vl[mt][rg] = rl < 2000;
            blv[mt][rg] = baseline[rrow*2000 + (rl < 2000 ? rl : 1999)];
        }

    #pragma unroll
    for (int nt = 0; nt < 4; ++nt) {
        v4f acc0 = (v4f){0.f,0.f,0.f,0.f}, acc1 = (v4f){0.f,0.f,0.f,0.f};
        #pragma unroll
        for (int kc = 0; kc < 4; ++kc) {
            v8s bh = as_v8s(dh[(nt*16 + n16)*16 + kc*4 + q]);
            v8s bl = as_v8s(dl[(nt*16 + n16)*16 + kc*4 + q]);
            acc0 = mfma16(af[0][kc], bh, acc0);
            acc1 = mfma16(af[1][kc], bh, acc1);
            acc0 = mfma16(af[0][kc], bl, acc0);
            acc1 = mfma16(af[1][kc], bl, acc1);
        }
        float m = -3.0e38f, s = 0.0f;
        #pragma unroll
        for (int rg = 0; rg < 4; ++rg) {
            float u = acc0[rg] + blv[0][rg];
            if (vl[0][rg]) {
                float mn = fmaxf(m, u);
                s = s * __expf(m - mn) + __expf(u - mn);
                m = mn;
            }
        }
        #pragma unroll
        for (int rg = 0; rg < 4; ++rg) {
            float u = acc1[rg] + blv[1][rg];
            if (vl[1][rg]) {
                float mn = fmaxf(m, u);
                s = s * __expf(m - mn) + __expf(u - mn);
                m = mn;
            }
        }
        #pragma unroll
        for (int off = 16; off < 64; off <<= 1) {
            float m2 = __shfl_xor(m, off, 64);
            float s2 = __shfl_xor(s, off, 64);
            float mn = fmaxf(m, m2);
            s = s * __expf(m - mn) + s2 * __expf(m2 - mn);
            m = mn;
        }
        if (q == 0) {
            sred[(w*64 + nt*16 + n16)*2 + 0] = m;
            sred[(w*64 + nt*16 + n16)*2 + 1] = s;
        }
    }
    __syncthreads();
    if (t < 64) {
        float m = sred[t*2 + 0], s = sred[t*2 + 1];
        #pragma unroll
        for (int ww = 1; ww < 4; ++ww) {
            float m2 = sred[(ww*64 + t)*2 + 0], s2 = sred[(ww*64 + t)*2 + 1];
            float mn = fmaxf(m, m2);
            s = s * __expf(m - mn) + s2 * __expf(m2 - mn);
            m = mn;
        }
        partials[((b*16 + chunk)*64 + t)*2 + 0] = m;
        partials[((b*16 + chunk)*64 + t)*2 + 1] = s;
    }
}

__global__ __launch_bounds__(64) void k_red(
    const float* __restrict__ partials, float* __restrict__ lse)
{
    int b = blockIdx.x, a = threadIdx.x;
    float m = -3.0e38f, s = 0.0f;
    for (int c = 0; c < 16; ++c) {
        float pm = partials[((b*16 + c)*64 + a)*2 + 0];
        float ps = partials[((b*16 + c)*64 + a)*2 + 1];
        float mn = fmaxf(m, pm);
        s = s * __expf(m - mn) + ps * __expf(pm - mn);
        m = mn;
    }
    lse[b*64 + a] = m + __logf(s);
}

// ---------------------------------------------------------------------------
// k_gather v6: 16 lanes cooperate on one fragment-row. Lane s reads uint4 at
// row offset s*16B -> coalesced 256-B segments; dot reduced via shfl_xor.
// ---------------------------------------------------------------------------
#define GR 4
__global__ __launch_bounds__(256) void k_gather(
    const u32* __restrict__ e, const float* __restrict__ diff,
    const float* __restrict__ baseline, const int* __restrict__ regions,
    const int* __restrict__ labels, const int* __restrict__ cellix,
    const int* __restrict__ regionix, const int* __restrict__ binix,
    const float* __restrict__ lse, float* __restrict__ out)
{
    const int t = threadIdx.x;
    const int g = t >> 4, s = t & 15;
    const int base = blockIdx.x * (16*GR) + g;
    #pragma unroll
    for (int p = 0; p < GR; ++p) {
        int f = base + p*16;
        bool valid = f < NF_;
        int fc = valid ? f : 0;
        int bb = regionix[fc];
        int l  = binix[fc];
        int a  = labels[cellix[fc]];
        uint4 pp = *(const uint4*)(e + ((size_t)(bb*2000 + l))*64 + s*4);
        const float4* d4 = (const float4*)(diff + a*128 + s*8);
        float4 d0 = d4[0], d1 = d4[1];
        float u0 = 0.f, u1 = 0.f;
        u0 += __uint_as_float(pp.x << 16)         * d0.x;
        u1 += __uint_as_float(pp.x & 0xffff0000u) * d0.y;
        u0 += __uint_as_float(pp.y << 16)         * d0.z;
        u1 += __uint_as_float(pp.y & 0xffff0000u) * d0.w;
        u0 += __uint_as_float(pp.z << 16)         * d1.x;
        u1 += __uint_as_float(pp.z & 0xffff0000u) * d1.y;
        u0 += __uint_as_float(pp.w << 16)         * d1.z;
        u1 += __uint_as_float(pp.w & 0xffff0000u) * d1.w;
        float u = u0 + u1;
        u += __shfl_xor(u, 1, 64);
        u += __shfl_xor(u, 2, 64);
        u += __shfl_xor(u, 4, 64);
        u += __shfl_xor(u, 8, 64);
        if (valid && s == 0) {
            float bl = baseline[regions[bb]*2000 + l];
            out[f] = u + bl - lse[bb*64 + a] + 5.545177444479562f;
        }
    }
}

extern "C" void kernel_launch(void* const* d_in, const int* in_sizes, int n_in,
                              void* d_out, int out_size, void* d_ws, size_t ws_size,
                              hipStream_t stream)
{
    const float* bincounts = (const float*)d_in[0];
    const float* conv1_w   = (const float*)d_in[1];
    const float* conv1_b   = (const float*)d_in[2];
    const float* conv2_w   = (const float*)d_in[3];
    const float* conv2_b   = (const float*)d_in[4];
    const float* lin1_w    = (const float*)d_in[5];
    const float* lin1_b    = (const float*)d_in[6];
    const float* lin2_w    = (const float*)d_in[7];
    const float* lin2_b    = (const float*)d_in[8];
    const float* baseline  = (const float*)d_in[9];
    const float* diff      = (const float*)d_in[10];
    const int*   regions   = (const int*)d_in[11];
    const int*   labels    = (const int*)d_in[12];
    const int*   cellix    = (const int*)d_in[13];
    const int*   regionix  = (const int*)d_in[14];
    const int*   binix     = (const int*)d_in[15];
    float* out = (float*)d_out;
    u32*   scr = (u32*)d_out;    // d_out doubles as scratch until k_gather

    const size_t e_words = (size_t)B_ * 2000 * 64;
    const size_t need = e_words*4 + (size_t)B_*64*4;
    if (ws_size < need) return;
    u32*   e   = (u32*)d_ws;
    float* lse = (float*)(e + e_words);

    const float* scf = (const float*)scr;
    float* partials = (float*)(scr + OFF_PART);

    w_prep <<<dim3(324), dim3(256), 0, stream>>>(bincounts, conv1_w, conv1_b, conv2_w,
                                                 conv2_b, lin1_w, lin2_w, diff, scr);
    k_front<<<dim3(B_*16), dim3(256), 0, stream>>>(bincounts, lin1_b, lin2_b,
                                                   scf + OFF_WCOMP, scf + OFF_BCOMP,
                                                   scf + OFF_VC,
                                                   (const uint4*)(scr + OFF_W1T_H),
                                                   (const uint4*)(scr + OFF_W1T_L),
                                                   (const uint4*)(scr + OFF_W2T_H),
                                                   (const uint4*)(scr + OFF_W2T_L),
                                                   (const uint4*)(scr + OFF_DIFF_H),
                                                   (const uint4*)(scr + OFF_DIFF_L),
                                                   baseline, regions, e, partials);
    k_red  <<<dim3(B_), dim3(64), 0, stream>>>(partials, lse);
    k_gather<<<dim3((NF_ + 16*GR - 1) / (16*GR)), dim3(256), 0, stream>>>(
        e, diff, baseline, regions, labels, cellix, regionix, binix, lse, out);
}

// Round 7
// 455.554 us; speedup vs baseline: 1.4411x; 1.0950x over previous
//
#include <hip/hip_runtime.h>
#include <stdint.h>

typedef unsigned int u32;
typedef short v8s __attribute__((ext_vector_type(8)));
typedef float v4f __attribute__((ext_vector_type(4)));

#define B_ 256
#define NF_ 1000000

__device__ inline u32 f2bf1(float a) {
    u32 x = __float_as_uint(a);
    return (x + 0x7fffu + ((x >> 16) & 1u)) >> 16;
}
__device__ inline float bfval(float a) { return __uint_as_float(f2bf1(a) << 16); }
__device__ inline u32 packbf(float lo, float hi) { return f2bf1(lo) | (f2bf1(hi) << 16); }
__device__ inline v8s as_v8s(uint4 x) { union { uint4 a; v8s b; } u; u.a = x; return u.b; }
__device__ inline v4f mfma16(v8s a, v8s b, v4f c) {
    return __builtin_amdgcn_mfma_f32_16x16x32_bf16(a, b, c, 0, 0, 0);
}
// wave-internal LDS write->read ordering: DS pipe is in-order per wave; drain
// lgkm + full compiler memory barrier. NOT a cross-wave sync.
__device__ inline void wave_lds_fence() {
    asm volatile("s_waitcnt lgkmcnt(0)" ::: "memory");
}

// truncation-split of 8 consecutive fp32 -> bf16 hi + lo frags (hi+lo exact)
__device__ inline void split8(const float* p, v8s& hi, v8s& lo) {
    u32 h[4], l[4];
    #pragma unroll
    for (int i = 0; i < 4; ++i) {
        float2 f = *(const float2*)(p + 2*i);
        u32 xa = __float_as_uint(f.x), xb = __float_as_uint(f.y);
        h[i] = __builtin_amdgcn_perm(xb, xa, 0x07060302u);
        float la = f.x - __uint_as_float(xa & 0xffff0000u);
        float lb = f.y - __uint_as_float(xb & 0xffff0000u);
        l[i] = __builtin_amdgcn_perm(__float_as_uint(lb), __float_as_uint(la), 0x07060302u);
    }
    hi = as_v8s(make_uint4(h[0], h[1], h[2], h[3]));
    lo = as_v8s(make_uint4(l[0], l[1], l[2], l[3]));
}

// d_out scratch layout (dword offsets)
#define OFF_W1T_H 0
#define OFF_W1T_L 4096
#define OFF_W2T_H 8192
#define OFF_W2T_L 16384
#define OFF_DIFF_H 24576
#define OFF_DIFF_L 28672
#define OFF_WCOMP 32768
#define OFF_BCOMP 33344
#define OFF_VC    33408
#define OFF_PART  131072

// ---------------------------------------------------------------------------
// w_prep (verified rounds 4-6)
// ---------------------------------------------------------------------------
__global__ __launch_bounds__(256) void w_prep(
    const float* __restrict__ x,   const float* __restrict__ w1c,
    const float* __restrict__ b1c, const float* __restrict__ w2c,
    const float* __restrict__ b2c, const float* __restrict__ w1l,
    const float* __restrict__ w2l, const float* __restrict__ diff,
    u32* __restrict__ scr)
{
    int idx = blockIdx.x * 256 + threadIdx.x;
    float* scf = (float*)scr;
    if (idx < 4096) {
        int j = idx >> 5, c = idx & 31;
        float v0 = w1l[j*64 + 2*c], v1 = w1l[j*64 + 2*c + 1];
        scr[OFF_W1T_H + idx] = packbf(v0, v1);
        scr[OFF_W1T_L + idx] = packbf(v0 - bfval(v0), v1 - bfval(v1));
    } else if (idx < 12288) {
        int r = idx - 4096, j = r >> 6, c = r & 63;
        float v0 = w2l[j*128 + 2*c], v1 = w2l[j*128 + 2*c + 1];
        scr[OFF_W2T_H + r] = packbf(v0, v1);
        scr[OFF_W2T_L + r] = packbf(v0 - bfval(v0), v1 - bfval(v1));
    } else if (idx < 16384) {
        int r = idx - 12288, a = r >> 6, c = r & 63;
        float v0 = diff[a*128 + 2*c], v1 = diff[a*128 + 2*c + 1];
        scr[OFF_DIFF_H + r] = packbf(v0, v1);
        scr[OFF_DIFF_L + r] = packbf(v0 - bfval(v0), v1 - bfval(v1));
    } else if (idx < 16960) {
        int r = idx - 16384, j = r >> 6, o = r & 63;
        float s = 0.0f;
        for (int k1 = 0; k1 < 5; ++k1) {
            int k2 = j - k1;
            if (k2 < 0 || k2 > 4) continue;
            for (int i = 0; i < 32; ++i)
                s += w1c[i*5 + k1] * w2c[o*160 + i*5 + k2];
        }
        scf[OFF_WCOMP + r] = s;
    } else if (idx < 17024) {
        int o = idx - 16960;
        float s = b2c[o];
        for (int i = 0; i < 32; ++i) {
            float b1 = b1c[i];
            for (int k2 = 0; k2 < 5; ++k2) s += w2c[o*160 + i*5 + k2] * b1;
        }
        scf[OFF_BCOMP + o] = s;
    } else if (idx >= 17408 && idx < 82944) {
        int r = idx - 17408;
        int b = r >> 8, q = (r >> 6) & 3, o = r & 63;
        float x0 = x[b*2000], x1 = x[b*2000 + 1];
        float xa = x[b*2000 + 1998], xb = x[b*2000 + 1999];
        float s = 0.0f;
        for (int i = 0; i < 32; ++i) {
            float b1 = b1c[i];
            if (q == 0) {
                float hvm2 = b1 + w1c[i*5 + 4]*x0;
                float hvm1 = b1 + w1c[i*5 + 3]*x0 + w1c[i*5 + 4]*x1;
                s += w2c[o*160 + i*5 + 0]*hvm2 + w2c[o*160 + i*5 + 1]*hvm1;
            } else if (q == 1) {
                float hvm1 = b1 + w1c[i*5 + 3]*x0 + w1c[i*5 + 4]*x1;
                s += w2c[o*160 + i*5 + 0]*hvm1;
            } else if (q == 2) {
                float hv0 = b1 + w1c[i*5 + 0]*xa + w1c[i*5 + 1]*xb;
                s += w2c[o*160 + i*5 + 4]*hv0;
            } else {
                float hv0 = b1 + w1c[i*5 + 0]*xa + w1c[i*5 + 1]*xb;
                float hv1 = b1 + w1c[i*5 + 0]*xb;
                s += w2c[o*160 + i*5 + 3]*hv0 + w2c[o*160 + i*5 + 4]*hv1;
            }
        }
        scf[OFF_VC + r] = s;
    }
}

// ---------------------------------------------------------------------------
// k_front v7 (wave-decoupled): each wave owns 32 rows end-to-end with a
// per-wave LDS tile; no __syncthreads until the final 4-wave (m,s) combine.
// conv fp32 -> lin1 (split-bf16 MFMA) -> lin2 -> e bf16 store -> lse GEMM.
// ---------------------------------------------------------------------------
__global__ __launch_bounds__(256, 3) void k_front(
    const float* __restrict__ x,  const float* __restrict__ b1l,
    const float* __restrict__ b2l,
    const float* __restrict__ Wc, const float* __restrict__ Bc,
    const float* __restrict__ Vc,
    const uint4* __restrict__ w1h, const uint4* __restrict__ w1lo,
    const uint4* __restrict__ w2h, const uint4* __restrict__ w2lo,
    const uint4* __restrict__ dh,  const uint4* __restrict__ dl,
    const float* __restrict__ baseline, const int* __restrict__ regions,
    u32* __restrict__ e, float* __restrict__ partials)
{
    // per wave: Awave [32][66] fp32 (2112) + xs [44] = 2156 dw; sred @ 8624
    __shared__ float smf[9136];
    const int b     = blockIdx.x >> 4;
    const int chunk = blockIdx.x & 15;
    const int t     = threadIdx.x;
    const int lane  = t & 63;
    const int w     = __builtin_amdgcn_readfirstlane(t >> 6);
    const int n16   = lane & 15;
    const int q     = lane >> 4;
    const int l0w   = (chunk << 7) + w*32;
    const int rrow  = regions[b];

    float* Aw   = smf + w*2156;
    float* xsw  = Aw + 2112;
    float* sred = smf + 8624;            // [4][64][2]
    u32*  estd  = (u32*)Aw;              // est overlay: [32][66] packed bf16
    uint16_t* esth = (uint16_t*)Aw;      // halfword view, row stride 132

    // per-wave halo load (no cross-wave dependence)
    if (lane < 40) {
        int g = l0w - 4 + lane;
        xsw[lane] = (g >= 0 && g < 2000) ? x[b*2000 + g] : 0.0f;
    }
    wave_lds_fence();

    // composite conv (exact fp32): lane = (row r = lane&31, half = lane>>5)
    {
        const int r = lane & 31;
        const int half = lane >> 5;
        const int gl = l0w + r;
        float xr[9];
        #pragma unroll
        for (int j = 0; j < 9; ++j) xr[j] = xsw[r + j];
        float yv[32];
        for (int oi = 0; oi < 32; ++oi) {
            int o = half*32 + oi;
            float y = Bc[o];
            #pragma unroll
            for (int j = 0; j < 9; ++j) y += xr[j] * Wc[j*64 + o];
            if (gl <= 1)                      y -= Vc[(b*4 + gl)*64 + o];
            else if (gl >= 1998 && gl < 2000) y -= Vc[(b*4 + gl - 1996)*64 + o];
            yv[oi] = y;
        }
        #pragma unroll
        for (int ci = 0; ci < 16; ++ci)
            *(float2*)&Aw[r*66 + half*32 + 2*ci] = make_float2(yv[2*ci], yv[2*ci+1]);
    }
    wave_lds_fence();

    // A1 frags (hi/lo), rows mt*16+n16 local — cached for both phases
    v8s a1h[2][2], a1l[2][2];
    #pragma unroll
    for (int mt = 0; mt < 2; ++mt)
        #pragma unroll
        for (int kc = 0; kc < 2; ++kc)
            split8(&Aw[(mt*16 + n16)*66 + kc*32 + q*8], a1h[mt][kc], a1l[mt][kc]);
    wave_lds_fence();

    v4f acc2[2][8];
    #pragma unroll
    for (int nt = 0; nt < 8; ++nt) {
        float bias = b2l[nt*16 + n16];
        acc2[0][nt] = (v4f){bias, bias, bias, bias};
        acc2[1][nt] = (v4f){bias, bias, bias, bias};
    }

    #pragma unroll
    for (int ph = 0; ph < 2; ++ph) {
        // lin1: out cols j = ph*64 + nt*16 + n16 -> Aw[.][0..63] fp32
        #pragma unroll
        for (int nt = 0; nt < 4; ++nt) {
            int j = ph*64 + nt*16 + n16;
            float bias = b1l[j];
            v4f a0 = (v4f){bias, bias, bias, bias};
            v4f a1v = a0;
            #pragma unroll
            for (int kc = 0; kc < 2; ++kc) {
                v8s bh = as_v8s(w1h [j*8 + kc*4 + q]);
                v8s bl = as_v8s(w1lo[j*8 + kc*4 + q]);
                a0  = mfma16(a1h[0][kc], bh, a0);
                a0  = mfma16(a1l[0][kc], bh, a0);
                a0  = mfma16(a1h[0][kc], bl, a0);
                a1v = mfma16(a1h[1][kc], bh, a1v);
                a1v = mfma16(a1l[1][kc], bh, a1v);
                a1v = mfma16(a1h[1][kc], bl, a1v);
            }
            #pragma unroll
            for (int rg = 0; rg < 4; ++rg) {
                Aw[(q*4 + rg)*66      + nt*16 + n16] = fmaxf(a0[rg], 0.0f);
                Aw[(16 + q*4 + rg)*66 + nt*16 + n16] = fmaxf(a1v[rg], 0.0f);
            }
        }
        wave_lds_fence();

        v8s a2h[2][2], a2l[2][2];
        #pragma unroll
        for (int mt = 0; mt < 2; ++mt)
            #pragma unroll
            for (int kcl = 0; kcl < 2; ++kcl)
                split8(&Aw[(mt*16 + n16)*66 + kcl*32 + q*8], a2h[mt][kcl], a2l[mt][kcl]);
        wave_lds_fence();

        #pragma unroll
        for (int nt = 0; nt < 8; ++nt) {
            int j2 = nt*16 + n16;
            #pragma unroll
            for (int kcl = 0; kcl < 2; ++kcl) {
                v8s bh = as_v8s(w2h [j2*16 + ph*8 + kcl*4 + q]);
                v8s bl = as_v8s(w2lo[j2*16 + ph*8 + kcl*4 + q]);
                acc2[0][nt] = mfma16(a2h[0][kcl], bh, acc2[0][nt]);
                acc2[0][nt] = mfma16(a2l[0][kcl], bh, acc2[0][nt]);
                acc2[0][nt] = mfma16(a2h[0][kcl], bl, acc2[0][nt]);
                acc2[1][nt] = mfma16(a2h[1][kcl], bh, acc2[1][nt]);
                acc2[1][nt] = mfma16(a2l[1][kcl], bh, acc2[1][nt]);
                acc2[1][nt] = mfma16(a2h[1][kcl], bl, acc2[1][nt]);
            }
        }
    }

    // epilogue: relu + RNE bf16 -> est (per-wave overlay)
    #pragma unroll
    for (int mt = 0; mt < 2; ++mt)
        #pragma unroll
        for (int nt = 0; nt < 8; ++nt)
            #pragma unroll
            for (int rg = 0; rg < 4; ++rg) {
                float v = fmaxf(acc2[mt][nt][rg], 0.0f);
                int rr = mt*16 + q*4 + rg;
                esth[rr*132 + nt*16 + n16] = (uint16_t)f2bf1(v);
            }
    wave_lds_fence();

    // e store: 1-KB contiguous per instruction (lane i -> row c*4+(i>>4))
    #pragma unroll
    for (int c = 0; c < 8; ++c) {
        int row = c*4 + (lane >> 4);
        int dwo = (lane & 15) * 4;
        int glr = l0w + row;
        if (glr < 2000) {
            uint2 p0 = *(const uint2*)(estd + row*66 + dwo);
            uint2 p1 = *(const uint2*)(estd + row*66 + dwo + 2);
            *(uint4*)(e + ((size_t)(b*2000 + glr))*64 + dwo) = make_uint4(p0.x, p0.y, p1.x, p1.y);
        }
    }

    // ---- fused lse on own 32-row slice ----
    v8s af[2][4];
    #pragma unroll
    for (int mt = 0; mt < 2; ++mt)
        #pragma unroll
        for (int kc = 0; kc < 4; ++kc) {
            int ba = (mt*16 + n16)*66 + kc*16 + q*4;
            uint2 p0 = *(const uint2*)(estd + ba);
            uint2 p1 = *(const uint2*)(estd + ba + 2);
            af[mt][kc] = as_v8s(make_uint4(p0.x, p0.y, p1.x, p1.y));
        }

    float blv[2][4];
    bool  vl[2][4];
    #pragma unroll
    for (int mt = 0; mt < 2; ++mt)
        #pragma unroll
        for (int rg = 0; rg < 4; ++rg) {
            int rl = l0w + mt*16 + q*4 + rg;
            vl[mt][rg] = rl < 2000;
            blv[mt][rg] = baseline[rrow*2000 + (rl < 2000 ? rl : 1999)];
        }

    #pragma unroll
    for (int nt = 0; nt < 4; ++nt) {
        v4f acc0 = (v4f){0.f,0.f,0.f,0.f}, acc1 = (v4f){0.f,0.f,0.f,0.f};
        #pragma unroll
        for (int kc = 0; kc < 4; ++kc) {
            v8s bh = as_v8s(dh[(nt*16 + n16)*16 + kc*4 + q]);
            v8s bl = as_v8s(dl[(nt*16 + n16)*16 + kc*4 + q]);
            acc0 = mfma16(af[0][kc], bh, acc0);
            acc1 = mfma16(af[1][kc], bh, acc1);
            acc0 = mfma16(af[0][kc], bl, acc0);
            acc1 = mfma16(af[1][kc], bl, acc1);
        }
        float m = -3.0e38f, s = 0.0f;
        #pragma unroll
        for (int rg = 0; rg < 4; ++rg) {
            float u = acc0[rg] + blv[0][rg];
            if (vl[0][rg]) {
                float mn = fmaxf(m, u);
                s = s * __expf(m - mn) + __expf(u - mn);
                m = mn;
            }
        }
        #pragma unroll
        for (int rg = 0; rg < 4; ++rg) {
            float u = acc1[rg] + blv[1][rg];
            if (vl[1][rg]) {
                float mn = fmaxf(m, u);
                s = s * __expf(m - mn) + __expf(u - mn);
                m = mn;
            }
        }
        #pragma unroll
        for (int off = 16; off < 64; off <<= 1) {
            float m2 = __shfl_xor(m, off, 64);
            float s2 = __shfl_xor(s, off, 64);
            float mn = fmaxf(m, m2);
            s = s * __expf(m - mn) + s2 * __expf(m2 - mn);
            m = mn;
        }
        if (q == 0) {
            sred[(w*64 + nt*16 + n16)*2 + 0] = m;
            sred[(w*64 + nt*16 + n16)*2 + 1] = s;
        }
    }
    __syncthreads();   // ONLY cross-wave sync in the kernel
    if (t < 64) {
        float m = sred[t*2 + 0], s = sred[t*2 + 1];
        #pragma unroll
        for (int ww = 1; ww < 4; ++ww) {
            float m2 = sred[(ww*64 + t)*2 + 0], s2 = sred[(ww*64 + t)*2 + 1];
            float mn = fmaxf(m, m2);
            s = s * __expf(m - mn) + s2 * __expf(m2 - mn);
            m = mn;
        }
        partials[((b*16 + chunk)*64 + t)*2 + 0] = m;
        partials[((b*16 + chunk)*64 + t)*2 + 1] = s;
    }
}

__global__ __launch_bounds__(64) void k_red(
    const float* __restrict__ partials, float* __restrict__ lse)
{
    int b = blockIdx.x, a = threadIdx.x;
    float m = -3.0e38f, s = 0.0f;
    for (int c = 0; c < 16; ++c) {
        float pm = partials[((b*16 + c)*64 + a)*2 + 0];
        float ps = partials[((b*16 + c)*64 + a)*2 + 1];
        float mn = fmaxf(m, pm);
        s = s * __expf(m - mn) + ps * __expf(pm - mn);
        m = mn;
    }
    lse[b*64 + a] = m + __logf(s);
}

// ---------------------------------------------------------------------------
// k_gather v7: cooperative 16-lane rows + batched index loads (GR independent
// load chains in flight).
// ---------------------------------------------------------------------------
#define GR 4
__global__ __launch_bounds__(256) void k_gather(
    const u32* __restrict__ e, const float* __restrict__ diff,
    const float* __restrict__ baseline, const int* __restrict__ regions,
    const int* __restrict__ labels, const int* __restrict__ cellix,
    const int* __restrict__ regionix, const int* __restrict__ binix,
    const float* __restrict__ lse, float* __restrict__ out)
{
    const int t = threadIdx.x;
    const int g = t >> 4, s = t & 15;
    const int base = blockIdx.x * (16*GR) + g;

    int f[GR], bb[GR], ll[GR], aa[GR];
    bool val[GR];
    #pragma unroll
    for (int p = 0; p < GR; ++p) {
        f[p] = base + p*16;
        val[p] = f[p] < NF_;
        int fc = val[p] ? f[p] : 0;
        bb[p] = regionix[fc];
        ll[p] = binix[fc];
        aa[p] = cellix[fc];
    }
    #pragma unroll
    for (int p = 0; p < GR; ++p) aa[p] = labels[aa[p]];

    uint4 pp[GR];
    #pragma unroll
    for (int p = 0; p < GR; ++p)
        pp[p] = *(const uint4*)(e + ((size_t)(bb[p]*2000 + ll[p]))*64 + s*4);

    #pragma unroll
    for (int p = 0; p < GR; ++p) {
        const float4* d4 = (const float4*)(diff + aa[p]*128 + s*8);
        float4 d0 = d4[0], d1 = d4[1];
        float u0 = 0.f, u1 = 0.f;
        u0 += __uint_as_float(pp[p].x << 16)         * d0.x;
        u1 += __uint_as_float(pp[p].x & 0xffff0000u) * d0.y;
        u0 += __uint_as_float(pp[p].y << 16)         * d0.z;
        u1 += __uint_as_float(pp[p].y & 0xffff0000u) * d0.w;
        u0 += __uint_as_float(pp[p].z << 16)         * d1.x;
        u1 += __uint_as_float(pp[p].z & 0xffff0000u) * d1.y;
        u0 += __uint_as_float(pp[p].w << 16)         * d1.z;
        u1 += __uint_as_float(pp[p].w & 0xffff0000u) * d1.w;
        float u = u0 + u1;
        u += __shfl_xor(u, 1, 64);
        u += __shfl_xor(u, 2, 64);
        u += __shfl_xor(u, 4, 64);
        u += __shfl_xor(u, 8, 64);
        if (val[p] && s == 0) {
            float bl = baseline[regions[bb[p]]*2000 + ll[p]];
            out[f[p]] = u + bl - lse[bb[p]*64 + aa[p]] + 5.545177444479562f;
        }
    }
}

extern "C" void kernel_launch(void* const* d_in, const int* in_sizes, int n_in,
                              void* d_out, int out_size, void* d_ws, size_t ws_size,
                              hipStream_t stream)
{
    const float* bincounts = (const float*)d_in[0];
    const float* conv1_w   = (const float*)d_in[1];
    const float* conv1_b   = (const float*)d_in[2];
    const float* conv2_w   = (const float*)d_in[3];
    const float* conv2_b   = (const float*)d_in[4];
    const float* lin1_w    = (const float*)d_in[5];
    const float* lin1_b    = (const float*)d_in[6];
    const float* lin2_w    = (const float*)d_in[7];
    const float* lin2_b    = (const float*)d_in[8];
    const float* baseline  = (const float*)d_in[9];
    const float* diff      = (const float*)d_in[10];
    const int*   regions   = (const int*)d_in[11];
    const int*   labels    = (const int*)d_in[12];
    const int*   cellix    = (const int*)d_in[13];
    const int*   regionix  = (const int*)d_in[14];
    const int*   binix     = (const int*)d_in[15];
    float* out = (float*)d_out;
    u32*   scr = (u32*)d_out;    // d_out doubles as scratch until k_gather

    const size_t e_words = (size_t)B_ * 2000 * 64;
    const size_t need = e_words*4 + (size_t)B_*64*4;
    if (ws_size < need) return;
    u32*   e   = (u32*)d_ws;
    float* lse = (float*)(e + e_words);

    const float* scf = (const float*)scr;
    float* partials = (float*)(scr + OFF_PART);

    w_prep <<<dim3(324), dim3(256), 0, stream>>>(bincounts, conv1_w, conv1_b, conv2_w,
                                                 conv2_b, lin1_w, lin2_w, diff, scr);
    k_front<<<dim3(B_*16), dim3(256), 0, stream>>>(bincounts, lin1_b, lin2_b,
                                                   scf + OFF_WCOMP, scf + OFF_BCOMP,
                                                   scf + OFF_VC,
                                                   (const uint4*)(scr + OFF_W1T_H),
                                                   (const uint4*)(scr + OFF_W1T_L),
                                                   (const uint4*)(scr + OFF_W2T_H),
                                                   (const uint4*)(scr + OFF_W2T_L),
                                                   (const uint4*)(scr + OFF_DIFF_H),
                                                   (const uint4*)(scr + OFF_DIFF_L),
                                                   baseline, regions, e, partials);
    k_red  <<<dim3(B_), dim3(64), 0, stream>>>(partials, lse);
    k_gather<<<dim3((NF_ + 16*GR - 1) / (16*GR)), dim3(256), 0, stream>>>(
        e, diff, baseline, regions, labels, cellix, regionix, binix, lse, out);
}

// Round 8
// 378.013 us; speedup vs baseline: 1.7368x; 1.2051x over previous
//
#include <hip/hip_runtime.h>
#include <stdint.h>

typedef unsigned int u32;
typedef short v8s __attribute__((ext_vector_type(8)));
typedef float v4f __attribute__((ext_vector_type(4)));

#define B_ 256
#define NF_ 1000000

__device__ inline u32 f2bf1(float a) {
    u32 x = __float_as_uint(a);
    return (x + 0x7fffu + ((x >> 16) & 1u)) >> 16;
}
__device__ inline float bfval(float a) { return __uint_as_float(f2bf1(a) << 16); }
__device__ inline u32 packbf(float lo, float hi) { return f2bf1(lo) | (f2bf1(hi) << 16); }
__device__ inline v8s as_v8s(uint4 x) { union { uint4 a; v8s b; } u; u.a = x; return u.b; }
__device__ inline v4f mfma16(v8s a, v8s b, v4f c) {
    return __builtin_amdgcn_mfma_f32_16x16x32_bf16(a, b, c, 0, 0, 0);
}
// wave-internal LDS write->read ordering (DS pipe in-order per wave)
__device__ inline void wave_lds_fence() {
    asm volatile("s_waitcnt lgkmcnt(0)" ::: "memory");
}

// truncation-split of 8 consecutive fp32 -> bf16 hi + lo frags (hi+lo exact)
__device__ inline void split8(const float* p, v8s& hi, v8s& lo) {
    u32 h[4], l[4];
    #pragma unroll
    for (int i = 0; i < 4; ++i) {
        float2 f = *(const float2*)(p + 2*i);
        u32 xa = __float_as_uint(f.x), xb = __float_as_uint(f.y);
        h[i] = __builtin_amdgcn_perm(xb, xa, 0x07060302u);
        float la = f.x - __uint_as_float(xa & 0xffff0000u);
        float lb = f.y - __uint_as_float(xb & 0xffff0000u);
        l[i] = __builtin_amdgcn_perm(__float_as_uint(lb), __float_as_uint(la), 0x07060302u);
    }
    hi = as_v8s(make_uint4(h[0], h[1], h[2], h[3]));
    lo = as_v8s(make_uint4(l[0], l[1], l[2], l[3]));
}

// d_out scratch layout (dword offsets)
#define OFF_W2T_H 8192       // [128][64]  lin2_w bf16-hi pairs
#define OFF_W2T_L 16384
#define OFF_DIFF_H 24576     // [64][64]   diff
#define OFF_DIFF_L 28672
#define OFF_WCOMP 32768      // [9][64]  composite conv weights (intermediate)
#define OFF_BCOMP 33344      // [64]
#define OFF_VC    33408      // [256][4][64] boundary corrections (intermediate)
#define OFF_CW    102400     // [9][128] fp32: lin1 @ Wcomp
#define OFF_CB1   103680     // [128]    fp32: lin1_b + lin1 @ Bcomp
#define OFF_PART  131072     // [256][16][64][2] lse partials
#define OFF_VC1   655360     // [256][4][128] fp32: lin1 @ Vc

// ---------------------------------------------------------------------------
// w_prep (verified rounds 4-7): w2/diff images + Wcomp/Bcomp/Vc
// ---------------------------------------------------------------------------
__global__ __launch_bounds__(256) void w_prep(
    const float* __restrict__ x,   const float* __restrict__ w1c,
    const float* __restrict__ b1c, const float* __restrict__ w2c,
    const float* __restrict__ b2c, const float* __restrict__ w2l,
    const float* __restrict__ diff, u32* __restrict__ scr)
{
    int idx = blockIdx.x * 256 + threadIdx.x;
    float* scf = (float*)scr;
    if (idx < 8192) {                        // w2T: [j][c=0..63]
        int j = idx >> 6, c = idx & 63;
        float v0 = w2l[j*128 + 2*c], v1 = w2l[j*128 + 2*c + 1];
        scr[OFF_W2T_H + idx] = packbf(v0, v1);
        scr[OFF_W2T_L + idx] = packbf(v0 - bfval(v0), v1 - bfval(v1));
    } else if (idx < 12288) {                // diff: [a][c=0..63]
        int r = idx - 8192, a = r >> 6, c = r & 63;
        float v0 = diff[a*128 + 2*c], v1 = diff[a*128 + 2*c + 1];
        scr[OFF_DIFF_H + r] = packbf(v0, v1);
        scr[OFF_DIFF_L + r] = packbf(v0 - bfval(v0), v1 - bfval(v1));
    } else if (idx < 12864) {                // Wcomp[tap=0..8][o]
        int r = idx - 12288, j = r >> 6, o = r & 63;
        float s = 0.0f;
        for (int k1 = 0; k1 < 5; ++k1) {
            int k2 = j - k1;
            if (k2 < 0 || k2 > 4) continue;
            for (int i = 0; i < 32; ++i)
                s += w1c[i*5 + k1] * w2c[o*160 + i*5 + k2];
        }
        scf[OFF_WCOMP + r] = s;
    } else if (idx < 12928) {                // Bcomp[o]
        int o = idx - 12864;
        float s = b2c[o];
        for (int i = 0; i < 32; ++i) {
            float b1 = b1c[i];
            for (int k2 = 0; k2 < 5; ++k2) s += w2c[o*160 + i*5 + k2] * b1;
        }
        scf[OFF_BCOMP + o] = s;
    } else if (idx >= 13056 && idx < 78592) {  // Vc[b][q][o]
        int r = idx - 13056;
        int b = r >> 8, q = (r >> 6) & 3, o = r & 63;
        float x0 = x[b*2000], x1 = x[b*2000 + 1];
        float xa = x[b*2000 + 1998], xb = x[b*2000 + 1999];
        float s = 0.0f;
        for (int i = 0; i < 32; ++i) {
            float b1 = b1c[i];
            if (q == 0) {
                float hvm2 = b1 + w1c[i*5 + 4]*x0;
                float hvm1 = b1 + w1c[i*5 + 3]*x0 + w1c[i*5 + 4]*x1;
                s += w2c[o*160 + i*5 + 0]*hvm2 + w2c[o*160 + i*5 + 1]*hvm1;
            } else if (q == 1) {
                float hvm1 = b1 + w1c[i*5 + 3]*x0 + w1c[i*5 + 4]*x1;
                s += w2c[o*160 + i*5 + 0]*hvm1;
            } else if (q == 2) {
                float hv0 = b1 + w1c[i*5 + 0]*xa + w1c[i*5 + 1]*xb;
                s += w2c[o*160 + i*5 + 4]*hv0;
            } else {
                float hv0 = b1 + w1c[i*5 + 0]*xa + w1c[i*5 + 1]*xb;
                float hv1 = b1 + w1c[i*5 + 0]*xb;
                s += w2c[o*160 + i*5 + 3]*hv0 + w2c[o*160 + i*5 + 4]*hv1;
            }
        }
        scf[OFF_VC + r] = s;
    }
}

// ---------------------------------------------------------------------------
// k_prep2: fold lin1 into the conv: CW = lin1 @ Wcomp, cb1 = b1l + lin1@Bcomp,
// Vc1 = Vc @ lin1^T. Exact fp32 (associativity-only change).
// ---------------------------------------------------------------------------
__global__ __launch_bounds__(256) void k_prep2(
    const float* __restrict__ w1l, const float* __restrict__ b1l,
    u32* __restrict__ scr)
{
    const float* scf = (const float*)scr;
    float* out = (float*)scr;
    int idx = blockIdx.x * 256 + threadIdx.x;
    if (idx < 1152) {                         // CW[tap][j]
        int tap = idx >> 7, j = idx & 127;
        float s = 0.f;
        for (int o = 0; o < 64; ++o)
            s += w1l[j*64 + o] * scf[OFF_WCOMP + tap*64 + o];
        out[OFF_CW + idx] = s;
    } else if (idx < 1280) {                  // cb1[j]
        int j = idx - 1152;
        float s = b1l[j];
        for (int o = 0; o < 64; ++o)
            s += w1l[j*64 + o] * scf[OFF_BCOMP + o];
        out[OFF_CB1 + j] = s;
    } else if (idx < 1280 + 131072) {         // Vc1[bq][j]
        int r = idx - 1280;
        int bq = r >> 7, j = r & 127;
        float s = 0.f;
        for (int o = 0; o < 64; ++o)
            s += w1l[j*64 + o] * scf[OFF_VC + bq*64 + o];
        out[OFF_VC1 + r] = s;
    }
}

// ---------------------------------------------------------------------------
// k_front v8: composite 9-tap conv (x -> relu(h1[128]), fp32, sliding window,
// 18 resident weights/lane) -> lin2 split-bf16 MFMA -> est bf16 -> e store +
// fused lse. Wave-private 32-row slice, conv in two 16-row sub-tiles.
// ---------------------------------------------------------------------------
__global__ __launch_bounds__(256, 3) void k_front(
    const float* __restrict__ x,   const float* __restrict__ b2l,
    const float* __restrict__ CW,  const float* __restrict__ cb1,
    const float* __restrict__ Vc1,
    const uint4* __restrict__ w2h, const uint4* __restrict__ w2lo,
    const uint4* __restrict__ dh,  const uint4* __restrict__ dl,
    const float* __restrict__ baseline, const int* __restrict__ regions,
    u32* __restrict__ e, float* __restrict__ partials)
{
    // per-wave region 2156 dw: conv [16][130] f32 / est [32][66] u32 overlay
    // (2112) + xs[44]; sred @ 8624
    __shared__ float smf[9136];
    const int b     = blockIdx.x >> 4;
    const int chunk = blockIdx.x & 15;
    const int t     = threadIdx.x;
    const int lane  = t & 63;
    const int w     = __builtin_amdgcn_readfirstlane(t >> 6);
    const int n16   = lane & 15;
    const int q     = lane >> 4;
    const int l0w   = (chunk << 7) + w*32;
    const int rrow  = regions[b];

    float* Aw   = smf + w*2156;
    float* xsw  = Aw + 2112;
    float* sred = smf + 8624;
    u32*  estd  = (u32*)Aw;              // est overlay [32][66]
    uint16_t* esth = (uint16_t*)Aw;      // halfword view, row stride 132

    // halo: x[l0w-4 .. l0w+39] (44 values; rows use up to +35+4)
    if (lane < 44) {
        int g = l0w - 4 + lane;
        xsw[lane] = (g >= 0 && g < 2000) ? x[b*2000 + g] : 0.0f;
    }
    wave_lds_fence();

    // resident composite weights: lane owns channels (2*lane, 2*lane+1)
    float cw0[9], cw1[9];
    #pragma unroll
    for (int d = 0; d < 9; ++d) {
        float2 c2 = *(const float2*)&CW[d*128 + 2*lane];
        cw0[d] = c2.x; cw1[d] = c2.y;
    }
    const float2 cb2 = *(const float2*)&cb1[2*lane];

    v8s a2h[2][4], a2l[2][4];
    #pragma unroll
    for (int mt = 0; mt < 2; ++mt) {
        // conv 16 rows (sliding window, LDS broadcast reads)
        float win[9];
        #pragma unroll
        for (int d = 0; d < 9; ++d) win[d] = xsw[mt*16 + d];
        for (int r = 0; r < 16; ++r) {
            int gl = l0w + mt*16 + r;
            float h0 = cb2.x, h1v = cb2.y;
            #pragma unroll
            for (int d = 0; d < 9; ++d) { h0 += win[d]*cw0[d]; h1v += win[d]*cw1[d]; }
            if (gl <= 1) {
                float2 v = *(const float2*)&Vc1[(b*4 + gl)*128 + 2*lane];
                h0 -= v.x; h1v -= v.y;
            } else if (gl >= 1998 && gl < 2000) {
                float2 v = *(const float2*)&Vc1[(b*4 + gl - 1996)*128 + 2*lane];
                h0 -= v.x; h1v -= v.y;
            }
            *(float2*)&Aw[r*130 + 2*lane] = make_float2(fmaxf(h0, 0.f), fmaxf(h1v, 0.f));
            #pragma unroll
            for (int d = 0; d < 8; ++d) win[d] = win[d+1];
            win[8] = xsw[mt*16 + r + 9];
        }
        wave_lds_fence();
        // A-frags (hi/lo) for this 16-row m-tile, K=128
        #pragma unroll
        for (int kc = 0; kc < 4; ++kc)
            split8(&Aw[n16*130 + kc*32 + q*8], a2h[mt][kc], a2l[mt][kc]);
        wave_lds_fence();    // frags read before next sub-tile overwrites
    }

    // lin2 + relu: M=32 N=128 K=128, split-bf16 (3-term)
    v4f acc2[2][8];
    #pragma unroll
    for (int nt = 0; nt < 8; ++nt) {
        float bias = b2l[nt*16 + n16];
        acc2[0][nt] = (v4f){bias, bias, bias, bias};
        acc2[1][nt] = (v4f){bias, bias, bias, bias};
    }
    #pragma unroll
    for (int nt = 0; nt < 8; ++nt) {
        int j2 = nt*16 + n16;
        #pragma unroll
        for (int kc = 0; kc < 4; ++kc) {
            v8s bh = as_v8s(w2h [j2*16 + kc*4 + q]);
            v8s bl = as_v8s(w2lo[j2*16 + kc*4 + q]);
            acc2[0][nt] = mfma16(a2h[0][kc], bh, acc2[0][nt]);
            acc2[0][nt] = mfma16(a2l[0][kc], bh, acc2[0][nt]);
            acc2[0][nt] = mfma16(a2h[0][kc], bl, acc2[0][nt]);
            acc2[1][nt] = mfma16(a2h[1][kc], bh, acc2[1][nt]);
            acc2[1][nt] = mfma16(a2l[1][kc], bh, acc2[1][nt]);
            acc2[1][nt] = mfma16(a2h[1][kc], bl, acc2[1][nt]);
        }
    }

    // epilogue: relu + RNE bf16 -> est
    #pragma unroll
    for (int mt = 0; mt < 2; ++mt)
        #pragma unroll
        for (int nt = 0; nt < 8; ++nt)
            #pragma unroll
            for (int rg = 0; rg < 4; ++rg) {
                float v = fmaxf(acc2[mt][nt][rg], 0.0f);
                int rr = mt*16 + q*4 + rg;
                esth[rr*132 + nt*16 + n16] = (uint16_t)f2bf1(v);
            }
    wave_lds_fence();

    // e store: coalesced 1-KB per instruction
    #pragma unroll
    for (int c = 0; c < 8; ++c) {
        int row = c*4 + (lane >> 4);
        int dwo = (lane & 15) * 4;
        int glr = l0w + row;
        if (glr < 2000) {
            uint2 p0 = *(const uint2*)(estd + row*66 + dwo);
            uint2 p1 = *(const uint2*)(estd + row*66 + dwo + 2);
            *(uint4*)(e + ((size_t)(b*2000 + glr))*64 + dwo) = make_uint4(p0.x, p0.y, p1.x, p1.y);
        }
    }

    // fused lse on own 32-row slice
    v8s af[2][4];
    #pragma unroll
    for (int mt = 0; mt < 2; ++mt)
        #pragma unroll
        for (int kc = 0; kc < 4; ++kc) {
            int ba = (mt*16 + n16)*66 + kc*16 + q*4;
            uint2 p0 = *(const uint2*)(estd + ba);
            uint2 p1 = *(const uint2*)(estd + ba + 2);
            af[mt][kc] = as_v8s(make_uint4(p0.x, p0.y, p1.x, p1.y));
        }

    float blv[2][4];
    bool  vl[2][4];
    #pragma unroll
    for (int mt = 0; mt < 2; ++mt)
        #pragma unroll
        for (int rg = 0; rg < 4; ++rg) {
            int rl = l0w + mt*16 + q*4 + rg;
            vl[mt][rg] = rl < 2000;
            blv[mt][rg] = baseline[rrow*2000 + (rl < 2000 ? rl : 1999)];
        }

    #pragma unroll
    for (int nt = 0; nt < 4; ++nt) {
        v4f acc0 = (v4f){0.f,0.f,0.f,0.f}, acc1 = (v4f){0.f,0.f,0.f,0.f};
        #pragma unroll
        for (int kc = 0; kc < 4; ++kc) {
            v8s bh = as_v8s(dh[(nt*16 + n16)*16 + kc*4 + q]);
            v8s bl = as_v8s(dl[(nt*16 + n16)*16 + kc*4 + q]);
            acc0 = mfma16(af[0][kc], bh, acc0);
            acc1 = mfma16(af[1][kc], bh, acc1);
            acc0 = mfma16(af[0][kc], bl, acc0);
            acc1 = mfma16(af[1][kc], bl, acc1);
        }
        float m = -3.0e38f, s = 0.0f;
        #pragma unroll
        for (int rg = 0; rg < 4; ++rg) {
            float u = acc0[rg] + blv[0][rg];
            if (vl[0][rg]) {
                float mn = fmaxf(m, u);
                s = s * __expf(m - mn) + __expf(u - mn);
                m = mn;
            }
        }
        #pragma unroll
        for (int rg = 0; rg < 4; ++rg) {
            float u = acc1[rg] + blv[1][rg];
            if (vl[1][rg]) {
                float mn = fmaxf(m, u);
                s = s * __expf(m - mn) + __expf(u - mn);
                m = mn;
            }
        }
        #pragma unroll
        for (int off = 16; off < 64; off <<= 1) {
            float m2 = __shfl_xor(m, off, 64);
            float s2 = __shfl_xor(s, off, 64);
            float mn = fmaxf(m, m2);
            s = s * __expf(m - mn) + s2 * __expf(m2 - mn);
            m = mn;
        }
        if (q == 0) {
            sred[(w*64 + nt*16 + n16)*2 + 0] = m;
            sred[(w*64 + nt*16 + n16)*2 + 1] = s;
        }
    }
    __syncthreads();
    if (t < 64) {
        float m = sred[t*2 + 0], s = sred[t*2 + 1];
        #pragma unroll
        for (int ww = 1; ww < 4; ++ww) {
            float m2 = sred[(ww*64 + t)*2 + 0], s2 = sred[(ww*64 + t)*2 + 1];
            float mn = fmaxf(m, m2);
            s = s * __expf(m - mn) + s2 * __expf(m2 - mn);
            m = mn;
        }
        partials[((b*16 + chunk)*64 + t)*2 + 0] = m;
        partials[((b*16 + chunk)*64 + t)*2 + 1] = s;
    }
}

__global__ __launch_bounds__(64) void k_red(
    const float* __restrict__ partials, float* __restrict__ lse)
{
    int b = blockIdx.x, a = threadIdx.x;
    float m = -3.0e38f, s = 0.0f;
    for (int c = 0; c < 16; ++c) {
        float pm = partials[((b*16 + c)*64 + a)*2 + 0];
        float ps = partials[((b*16 + c)*64 + a)*2 + 1];
        float mn = fmaxf(m, pm);
        s = s * __expf(m - mn) + ps * __expf(pm - mn);
        m = mn;
    }
    lse[b*64 + a] = m + __logf(s);
}

// ---------------------------------------------------------------------------
// k_gather (v7, verified): cooperative 16-lane rows + batched index loads
// ---------------------------------------------------------------------------
#define GR 4
__global__ __launch_bounds__(256) void k_gather(
    const u32* __restrict__ e, const float* __restrict__ diff,
    const float* __restrict__ baseline, const int* __restrict__ regions,
    const int* __restrict__ labels, const int* __restrict__ cellix,
    const int* __restrict__ regionix, const int* __restrict__ binix,
    const float* __restrict__ lse, float* __restrict__ out)
{
    const int t = threadIdx.x;
    const int g = t >> 4, s = t & 15;
    const int base = blockIdx.x * (16*GR) + g;

    int f[GR], bb[GR], ll[GR], aa[GR];
    bool val[GR];
    #pragma unroll
    for (int p = 0; p < GR; ++p) {
        f[p] = base + p*16;
        val[p] = f[p] < NF_;
        int fc = val[p] ? f[p] : 0;
        bb[p] = regionix[fc];
        ll[p] = binix[fc];
        aa[p] = cellix[fc];
    }
    #pragma unroll
    for (int p = 0; p < GR; ++p) aa[p] = labels[aa[p]];

    uint4 pp[GR];
    #pragma unroll
    for (int p = 0; p < GR; ++p)
        pp[p] = *(const uint4*)(e + ((size_t)(bb[p]*2000 + ll[p]))*64 + s*4);

    #pragma unroll
    for (int p = 0; p < GR; ++p) {
        const float4* d4 = (const float4*)(diff + aa[p]*128 + s*8);
        float4 d0 = d4[0], d1 = d4[1];
        float u0 = 0.f, u1 = 0.f;
        u0 += __uint_as_float(pp[p].x << 16)         * d0.x;
        u1 += __uint_as_float(pp[p].x & 0xffff0000u) * d0.y;
        u0 += __uint_as_float(pp[p].y << 16)         * d0.z;
        u1 += __uint_as_float(pp[p].y & 0xffff0000u) * d0.w;
        u0 += __uint_as_float(pp[p].z << 16)         * d1.x;
        u1 += __uint_as_float(pp[p].z & 0xffff0000u) * d1.y;
        u0 += __uint_as_float(pp[p].w << 16)         * d1.z;
        u1 += __uint_as_float(pp[p].w & 0xffff0000u) * d1.w;
        float u = u0 + u1;
        u += __shfl_xor(u, 1, 64);
        u += __shfl_xor(u, 2, 64);
        u += __shfl_xor(u, 4, 64);
        u += __shfl_xor(u, 8, 64);
        if (val[p] && s == 0) {
            float bl = baseline[regions[bb[p]]*2000 + ll[p]];
            out[f[p]] = u + bl - lse[bb[p]*64 + aa[p]] + 5.545177444479562f;
        }
    }
}

extern "C" void kernel_launch(void* const* d_in, const int* in_sizes, int n_in,
                              void* d_out, int out_size, void* d_ws, size_t ws_size,
                              hipStream_t stream)
{
    const float* bincounts = (const float*)d_in[0];
    const float* conv1_w   = (const float*)d_in[1];
    const float* conv1_b   = (const float*)d_in[2];
    const float* conv2_w   = (const float*)d_in[3];
    const float* conv2_b   = (const float*)d_in[4];
    const float* lin1_w    = (const float*)d_in[5];
    const float* lin1_b    = (const float*)d_in[6];
    const float* lin2_w    = (const float*)d_in[7];
    const float* lin2_b    = (const float*)d_in[8];
    const float* baseline  = (const float*)d_in[9];
    const float* diff      = (const float*)d_in[10];
    const int*   regions   = (const int*)d_in[11];
    const int*   labels    = (const int*)d_in[12];
    const int*   cellix    = (const int*)d_in[13];
    const int*   regionix  = (const int*)d_in[14];
    const int*   binix     = (const int*)d_in[15];
    float* out = (float*)d_out;
    u32*   scr = (u32*)d_out;    // d_out doubles as scratch until k_gather

    const size_t e_words = (size_t)B_ * 2000 * 64;
    const size_t need = e_words*4 + (size_t)B_*64*4;
    if (ws_size < need) return;
    u32*   e   = (u32*)d_ws;
    float* lse = (float*)(e + e_words);

    const float* scf = (const float*)scr;
    float* partials = (float*)(scr + OFF_PART);

    w_prep <<<dim3(307), dim3(256), 0, stream>>>(bincounts, conv1_w, conv1_b, conv2_w,
                                                 conv2_b, lin2_w, diff, scr);
    k_prep2<<<dim3(518), dim3(256), 0, stream>>>(lin1_w, lin1_b, scr);
    k_front<<<dim3(B_*16), dim3(256), 0, stream>>>(bincounts, lin2_b,
                                                   scf + OFF_CW, scf + OFF_CB1,
                                                   scf + OFF_VC1,
                                                   (const uint4*)(scr + OFF_W2T_H),
                                                   (const uint4*)(scr + OFF_W2T_L),
                                                   (const uint4*)(scr + OFF_DIFF_H),
                                                   (const uint4*)(scr + OFF_DIFF_L),
                                                   baseline, regions, e, partials);
    k_red  <<<dim3(B_), dim3(64), 0, stream>>>(partials, lse);
    k_gather<<<dim3((NF_ + 16*GR - 1) / (16*GR)), dim3(256), 0, stream>>>(
        e, diff, baseline, regions, labels, cellix, regionix, binix, lse, out);
}